// Round 3
// baseline (323.635 us; speedup 1.0000x reference)
//
#include <hip/hip_runtime.h>
#include <math.h>

#define G 5000
#define IN 64
#define D 128
#define E 240000
#define EG (E + G)
#define SLOPE 0.2f
#define GD (G * D)

#define NB_PG 1250                 // pergene blocks (4 genes each)
#define NB_H  ((EG + 255) / 256)   // 958 hist blocks
#define NB_A  (NB_PG + NB_H)
#define GPB 8
#define NB_X (G / GPB)             // 625 xlxr blocks
#define NB_M 1250                  // mlp1 blocks (512 rows each)

__device__ __forceinline__ float leaky(float v) { return v >= 0.f ? v : SLOPE * v; }

// ---------------- K_A: per-gene linear (float4, 2 rows/iter) + dst histogram ----------------
__global__ __launch_bounds__(256) void k_fuseA(const float* __restrict__ x,
                                               const float* __restrict__ Win,
                                               const float* __restrict__ bin,
                                               float* __restrict__ h,
                                               const int* __restrict__ dstA,
                                               int* __restrict__ cnt) {
    if (blockIdx.x < NB_PG) {
        int g = blockIdx.x * 4 + (threadIdx.x >> 6);
        int lane = threadIdx.x & 63;
        int half = lane >> 5, l5 = lane & 31;
        float xv = x[g * IN + lane];
        const float* W = Win + (size_t)g * (IN * D) + half * D + l5 * 4;
        float4 acc = {0.f, 0.f, 0.f, 0.f};
#pragma unroll 8
        for (int ip = 0; ip < 32; ++ip) {
            float xi = __shfl(xv, 2 * ip + half);
            float4 w4 = *(const float4*)(W + (size_t)ip * (2 * D));
            acc.x = fmaf(xi, w4.x, acc.x);
            acc.y = fmaf(xi, w4.y, acc.y);
            acc.z = fmaf(xi, w4.z, acc.z);
            acc.w = fmaf(xi, w4.w, acc.w);
        }
        acc.x += __shfl_xor(acc.x, 32);
        acc.y += __shfl_xor(acc.y, 32);
        acc.z += __shfl_xor(acc.z, 32);
        acc.w += __shfl_xor(acc.w, 32);
        if (half == 0) {
            float4 b4 = *(const float4*)(bin + g * D + l5 * 4);
            float4 o = { fmaxf(acc.x + b4.x, 0.f), fmaxf(acc.y + b4.y, 0.f),
                         fmaxf(acc.z + b4.z, 0.f), fmaxf(acc.w + b4.w, 0.f) };
            *(float4*)(h + g * D + l5 * 4) = o;
        }
    } else {
        int i = (blockIdx.x - NB_PG) * 256 + threadIdx.x;
        if (i < EG) {
            int t = (i < E) ? dstA[i] : i - E;
            atomicAdd(&cnt[t], 1);
        }
    }
}

// ---------------- K_B: block 0 = exclusive scan; blocks 1.. = xlxr ----------------
__global__ __launch_bounds__(256) void k_fuseB(const int* __restrict__ cnt,
                                               int* __restrict__ rowptr,
                                               int* __restrict__ cursor,
                                               const float* __restrict__ hbuf,
                                               const float* __restrict__ Wl,
                                               const float* __restrict__ bl,
                                               const float* __restrict__ Wr,
                                               const float* __restrict__ br,
                                               float* __restrict__ xl,
                                               float* __restrict__ xr) {
    if (blockIdx.x == 0) {
        __shared__ int ssum[256];
        int tid = threadIdx.x;
        const int CH = (G + 255) / 256;   // 20
        int base = tid * CH;
        int s = 0;
        for (int k = 0; k < CH; ++k) { int idx = base + k; if (idx < G) s += cnt[idx]; }
        ssum[tid] = s;
        __syncthreads();
        for (int off = 1; off < 256; off <<= 1) {
            int v = ssum[tid];
            int add = (tid >= off) ? ssum[tid - off] : 0;
            __syncthreads();
            ssum[tid] = v + add;
            __syncthreads();
        }
        int run = (tid == 0) ? 0 : ssum[tid - 1];
        for (int k = 0; k < CH; ++k) {
            int idx = base + k;
            if (idx < G) { rowptr[idx] = run; cursor[idx] = run; run += cnt[idx]; }
        }
        if (tid == 255) rowptr[G] = run;   // == EG
    } else {
        int g0 = (blockIdx.x - 1) * GPB;
        __shared__ float hs[GPB][D];
        for (int idx = threadIdx.x; idx < GPB * D; idx += 256)
            hs[idx >> 7][idx & 127] = hbuf[g0 * D + idx];
        __syncthreads();
        int c2 = (threadIdx.x & 63) * 2;
        int p  = threadIdx.x >> 6;          // genes p and p+4
        float2 blv = *(const float2*)(bl + c2);
        float2 brv = *(const float2*)(br + c2);
        float2 al0 = blv, al1 = blv, ar0 = brv, ar1 = brv;
        for (int k = 0; k < D; ++k) {
            float2 wl2 = *(const float2*)(Wl + k * D + c2);
            float2 wr2 = *(const float2*)(Wr + k * D + c2);
            float h0 = hs[p][k], h1 = hs[p + 4][k];
            al0.x = fmaf(h0, wl2.x, al0.x); al0.y = fmaf(h0, wl2.y, al0.y);
            ar0.x = fmaf(h0, wr2.x, ar0.x); ar0.y = fmaf(h0, wr2.y, ar0.y);
            al1.x = fmaf(h1, wl2.x, al1.x); al1.y = fmaf(h1, wl2.y, al1.y);
            ar1.x = fmaf(h1, wr2.x, ar1.x); ar1.y = fmaf(h1, wr2.y, ar1.y);
        }
        *(float2*)(xl + (g0 + p) * D + c2)     = al0;
        *(float2*)(xr + (g0 + p) * D + c2)     = ar0;
        *(float2*)(xl + (g0 + p + 4) * D + c2) = al1;
        *(float2*)(xr + (g0 + p + 4) * D + c2) = ar1;
    }
}

// ---------------- K_C: bucket edges by destination ----------------
__global__ __launch_bounds__(256) void k_bucket(const int* __restrict__ srcA,
                                                const int* __restrict__ dstA,
                                                int* __restrict__ cursor,
                                                int* __restrict__ ssrc) {
    int i = blockIdx.x * 256 + threadIdx.x;
    if (i >= EG) return;
    int s, t;
    if (i < E) { s = srcA[i]; t = dstA[i]; }
    else { s = i - E; t = s; }
    int pos = atomicAdd(&cursor[t], 1);
    ssrc[pos] = s;
}

// ---------------- K_D: GAT aggregation, one wave per dest, 2 edges/iter ----------------
__global__ __launch_bounds__(256) void k_agg(const int* __restrict__ rowptr,
                                             const int* __restrict__ ssrc,
                                             const float* __restrict__ xl,
                                             const float* __restrict__ xr,
                                             const float* __restrict__ att,
                                             const float* __restrict__ bias,
                                             float* __restrict__ f) {
    int t = (blockIdx.x * 256 + threadIdx.x) >> 6;
    int lane = threadIdx.x & 63;
    int half = lane >> 5, l5 = lane & 31;
    if (t >= G) return;
    float4 a4 = *(const float4*)(att + l5 * 4);
    float4 r4 = *(const float4*)(xr + t * D + l5 * 4);
    float4 acc = {0.f, 0.f, 0.f, 0.f};
    float z = 0.f;
    int e0 = rowptr[t], e1 = rowptr[t + 1];
    for (int base = e0; base < e1; base += 2) {
        int idx = base + half;
        int ic = min(idx, e1 - 1);
        int s = ssrc[ic];
        float4 l4 = *(const float4*)(xl + s * D + l5 * 4);
        float v = leaky(l4.x + r4.x) * a4.x + leaky(l4.y + r4.y) * a4.y
                + leaky(l4.z + r4.z) * a4.z + leaky(l4.w + r4.w) * a4.w;
        v += __shfl_xor(v, 16); v += __shfl_xor(v, 8);
        v += __shfl_xor(v, 4);  v += __shfl_xor(v, 2); v += __shfl_xor(v, 1);
        float w = (idx < e1) ? expf(v) : 0.f;
        z += w;
        acc.x = fmaf(w, l4.x, acc.x);
        acc.y = fmaf(w, l4.y, acc.y);
        acc.z = fmaf(w, l4.z, acc.z);
        acc.w = fmaf(w, l4.w, acc.w);
    }
    z     += __shfl_xor(z, 32);
    acc.x += __shfl_xor(acc.x, 32);
    acc.y += __shfl_xor(acc.y, 32);
    acc.z += __shfl_xor(acc.z, 32);
    acc.w += __shfl_xor(acc.w, 32);
    if (half == 0) {
        float4 b4 = *(const float4*)(bias + l5 * 4);
        float inv = 1.f / z;
        float4 o = { leaky(acc.x * inv + b4.x), leaky(acc.y * inv + b4.y),
                     leaky(acc.z * inv + b4.z), leaky(acc.w * inv + b4.w) };
        *(float4*)(f + t * D + l5 * 4) = o;
    }
}

// ---------------- K_E: MLP layer 1 (float4, 2 rows/iter, 512 rows/block) ----------------
__global__ __launch_bounds__(256) void k_mlp1(const float* __restrict__ f,
                                              const float* __restrict__ W1,
                                              float* __restrict__ partials) {
    int w = threadIdx.x >> 6, lane = threadIdx.x & 63;
    int half = lane >> 5, l5 = lane & 31;
    int rbase = blockIdx.x * 512 + w * 128;
    float fq0 = f[rbase + lane];
    float fq1 = f[rbase + 64 + lane];
    const float* Wp = W1 + (size_t)rbase * D + half * D + l5 * 4;
    float4 acc = {0.f, 0.f, 0.f, 0.f};
#pragma unroll 8
    for (int it = 0; it < 32; ++it) {
        float xi = __shfl(fq0, 2 * it + half);
        float4 w4 = *(const float4*)(Wp + (size_t)it * (2 * D));
        acc.x = fmaf(xi, w4.x, acc.x);
        acc.y = fmaf(xi, w4.y, acc.y);
        acc.z = fmaf(xi, w4.z, acc.z);
        acc.w = fmaf(xi, w4.w, acc.w);
    }
    const float* Wp2 = Wp + (size_t)64 * D;
#pragma unroll 8
    for (int it = 0; it < 32; ++it) {
        float xi = __shfl(fq1, 2 * it + half);
        float4 w4 = *(const float4*)(Wp2 + (size_t)it * (2 * D));
        acc.x = fmaf(xi, w4.x, acc.x);
        acc.y = fmaf(xi, w4.y, acc.y);
        acc.z = fmaf(xi, w4.z, acc.z);
        acc.w = fmaf(xi, w4.w, acc.w);
    }
    acc.x += __shfl_xor(acc.x, 32);
    acc.y += __shfl_xor(acc.y, 32);
    acc.z += __shfl_xor(acc.z, 32);
    acc.w += __shfl_xor(acc.w, 32);
    __shared__ float4 red[4][32];
    if (half == 0) red[w][l5] = acc;
    __syncthreads();
    if (w == 0 && half == 0) {
        float4 s0 = red[0][l5], s1 = red[1][l5], s2 = red[2][l5], s3 = red[3][l5];
        float4 s = { s0.x + s1.x + s2.x + s3.x, s0.y + s1.y + s2.y + s3.y,
                     s0.z + s1.z + s2.z + s3.z, s0.w + s1.w + s2.w + s3.w };
        *(float4*)(partials + blockIdx.x * D + l5 * 4) = s;
    }
}

// ---------------- K_F: reduce partials + relu + dot W2 ----------------
__global__ __launch_bounds__(256) void k_final(const float* __restrict__ partials,
                                               const float* __restrict__ b1,
                                               const float* __restrict__ W2,
                                               const float* __restrict__ b2,
                                               float* __restrict__ out) {
    int tid = threadIdx.x;
    int j = tid & 127, seg = tid >> 7;
    float s = 0.f;
    for (int b = seg; b < NB_M; b += 2) s += partials[b * D + j];
    __shared__ float red[256];
    red[tid] = s;
    __syncthreads();
    if (tid < 128) {
        float tot = red[tid] + red[128 + tid];
        float h1 = fmaxf(tot + b1[tid], 0.f);
        red[tid] = h1 * W2[tid];
    }
    __syncthreads();
    if (tid == 0) {
        float o = b2[0];
        for (int k = 0; k < 128; ++k) o += red[k];
        out[0] = o;
    }
}

extern "C" void kernel_launch(void* const* d_in, const int* in_sizes, int n_in,
                              void* d_out, int out_size, void* d_ws, size_t ws_size,
                              hipStream_t stream) {
    const float* x    = (const float*)d_in[0];
    const int*   ei   = (const int*)d_in[1];
    const float* Win  = (const float*)d_in[2];
    const float* bin  = (const float*)d_in[3];
    const float* Wl   = (const float*)d_in[4];
    const float* bl   = (const float*)d_in[5];
    const float* Wr   = (const float*)d_in[6];
    const float* br   = (const float*)d_in[7];
    const float* att  = (const float*)d_in[8];
    const float* bias = (const float*)d_in[9];
    const float* W1   = (const float*)d_in[10];
    const float* b1   = (const float*)d_in[11];
    const float* W2   = (const float*)d_in[12];
    const float* b2   = (const float*)d_in[13];
    float* out = (float*)d_out;

    float* ws       = (float*)d_ws;
    float* h        = ws;                  // GD
    float* xl       = h  + GD;             // GD
    float* xr       = xl + GD;             // GD
    float* f        = xr + GD;             // GD
    float* partials = f  + GD;             // NB_M * D
    int*   ssrc     = (int*)(partials + (size_t)NB_M * D);  // EG
    int*   cnt      = ssrc + EG;           // G
    int*   rowptr   = cnt + G;             // G+1
    int*   cursor   = rowptr + G + 1;      // G

    const int* srcA = ei;
    const int* dstA = ei + E;

    hipMemsetAsync(cnt, 0, G * sizeof(int), stream);
    k_fuseA<<<NB_A, 256, 0, stream>>>(x, Win, bin, h, dstA, cnt);
    k_fuseB<<<NB_X + 1, 256, 0, stream>>>(cnt, rowptr, cursor, h, Wl, bl, Wr, br, xl, xr);
    k_bucket<<<NB_H, 256, 0, stream>>>(srcA, dstA, cursor, ssrc);
    k_agg<<<(G * 64 + 255) / 256, 256, 0, stream>>>(rowptr, ssrc, xl, xr, att, bias, f);
    k_mlp1<<<NB_M, 256, 0, stream>>>(f, W1, partials);
    k_final<<<1, 256, 0, stream>>>(partials, b1, W2, b2, out);
}